// Round 2
// baseline (141.377 us; speedup 1.0000x reference)
//
#include <hip/hip_runtime.h>

#define BB 8
#define CCH 19
#define HH 512
#define WW 1024
#define HW (HH * WW)          // 524288
#define NPIX (BB * HW)        // 4194304
#define CHW (CCH * HW)
#define N4 (NPIX / 4)         // 1048576

#define FIX_SCALE 17179869184.0   // 2^34

struct SelState {
    unsigned num;
    unsigned b1, k1;
    unsigned b2, k2;
};

__device__ __forceinline__ unsigned fkey(float x) {
    unsigned u = __float_as_uint(x);
    return (u & 0x80000000u) ? ~u : (u | 0x80000000u);
}

__device__ __forceinline__ unsigned long long fix64(float x) {
    return (unsigned long long)((double)x * FIX_SCALE);
}

// ---- init: zero all small global state + compute num from step ----
__global__ __launch_bounds__(256) void k_init(const int* __restrict__ step_p,
                                              unsigned* __restrict__ zbase,
                                              SelState* st) {
    // zero 7172 words: hist1(2048) hist2(2048) h3(1024) bs(2048) above(3+pad)
    for (int i = threadIdx.x; i < 7172; i += 256) zbase[i] = 0u;
    if (threadIdx.x == 0) {
        int step = step_p[0];
        double m = pow(0.99998, (double)step);
        double Kc = 0.15;
        double f = m > Kc ? m : Kc;
        st->num = (unsigned)(Kc * (double)BB * (double)HH * (double)WW * f);
    }
}

// ---- pass 1: per-pixel CE (float4) + fused 11-bit histogram ----
__global__ __launch_bounds__(256) void k_loss_hist(const float* __restrict__ pred,
                                                   const int* __restrict__ target,
                                                   float* __restrict__ loss,
                                                   unsigned* __restrict__ hist) {
    __shared__ unsigned h[2048];
    for (int i = threadIdx.x; i < 2048; i += 256) h[i] = 0;
    __syncthreads();

    int stride = gridDim.x * 256;
    for (int i4 = blockIdx.x * 256 + threadIdx.x; i4 < N4; i4 += stride) {
        int p0 = i4 << 2;
        int b = p0 >> 19;           // / HW
        int hw = p0 & (HW - 1);
        const float* base = pred + (size_t)b * CHW + hw;

        float4 v[CCH];
#pragma unroll
        for (int c = 0; c < CCH; ++c)
            v[c] = *reinterpret_cast<const float4*>(base + (size_t)c * HW);
        int4 tg = *reinterpret_cast<const int4*>(target + p0);

        float4 mx = v[0];
#pragma unroll
        for (int c = 1; c < CCH; ++c) {
            mx.x = fmaxf(mx.x, v[c].x);
            mx.y = fmaxf(mx.y, v[c].y);
            mx.z = fmaxf(mx.z, v[c].z);
            mx.w = fmaxf(mx.w, v[c].w);
        }
        float4 s = make_float4(0.f, 0.f, 0.f, 0.f);
        float4 xt = make_float4(0.f, 0.f, 0.f, 0.f);
#pragma unroll
        for (int c = 0; c < CCH; ++c) {
            s.x += __expf(v[c].x - mx.x);
            s.y += __expf(v[c].y - mx.y);
            s.z += __expf(v[c].z - mx.z);
            s.w += __expf(v[c].w - mx.w);
            xt.x = (tg.x == c) ? v[c].x : xt.x;
            xt.y = (tg.y == c) ? v[c].y : xt.y;
            xt.z = (tg.z == c) ? v[c].z : xt.z;
            xt.w = (tg.w == c) ? v[c].w : xt.w;
        }
        float4 o;
        o.x = __logf(s.x) + mx.x - xt.x;
        o.y = __logf(s.y) + mx.y - xt.y;
        o.z = __logf(s.z) + mx.z - xt.z;
        o.w = __logf(s.w) + mx.w - xt.w;
        *reinterpret_cast<float4*>(loss + p0) = o;

        atomicAdd(&h[fkey(o.x) >> 21], 1u);
        atomicAdd(&h[fkey(o.y) >> 21], 1u);
        atomicAdd(&h[fkey(o.z) >> 21], 1u);
        atomicAdd(&h[fkey(o.w) >> 21], 1u);
    }
    __syncthreads();
    for (int i = threadIdx.x; i < 2048; i += 256) {
        unsigned c = h[i];
        if (c) atomicAdd(&hist[i], c);
    }
}

// ---- pass 2 histogram: middle 11 bits for elements in bin b1 ----
__global__ __launch_bounds__(256) void k_histB(const float* __restrict__ loss,
                                               const SelState* __restrict__ st,
                                               unsigned* __restrict__ hist) {
    __shared__ unsigned h[2048];
    for (int i = threadIdx.x; i < 2048; i += 256) h[i] = 0;
    __syncthreads();
    unsigned b1 = st->b1;
    int stride = gridDim.x * 256;
    for (int i4 = blockIdx.x * 256 + threadIdx.x; i4 < N4; i4 += stride) {
        float4 v = reinterpret_cast<const float4*>(loss)[i4];
        unsigned u;
        u = fkey(v.x); if ((u >> 21) == b1) atomicAdd(&h[(u >> 10) & 2047u], 1u);
        u = fkey(v.y); if ((u >> 21) == b1) atomicAdd(&h[(u >> 10) & 2047u], 1u);
        u = fkey(v.z); if ((u >> 21) == b1) atomicAdd(&h[(u >> 10) & 2047u], 1u);
        u = fkey(v.w); if ((u >> 21) == b1) atomicAdd(&h[(u >> 10) & 2047u], 1u);
    }
    __syncthreads();
    for (int i = threadIdx.x; i < 2048; i += 256) {
        unsigned c = h[i];
        if (c) atomicAdd(&hist[i], c);
    }
}

// ---- pass 3: low-10-bit histogram + per-bin fixed-point sums for
//      prefix-matching elements; sum/count of strictly-above elements ----
__global__ __launch_bounds__(256) void k_histC(const float* __restrict__ loss,
                                               const SelState* __restrict__ st,
                                               unsigned* __restrict__ h3g,
                                               unsigned long long* __restrict__ bsg,
                                               unsigned long long* __restrict__ aboveSum,
                                               unsigned* __restrict__ aboveCnt) {
    __shared__ unsigned h[1024];
    __shared__ unsigned long long bs[1024];
    for (int i = threadIdx.x; i < 1024; i += 256) { h[i] = 0; bs[i] = 0ull; }
    __syncthreads();
    unsigned pref22 = (st->b1 << 11) | st->b2;
    unsigned long long asum = 0ull;
    unsigned acnt = 0;
    int stride = gridDim.x * 256;
    for (int i4 = blockIdx.x * 256 + threadIdx.x; i4 < N4; i4 += stride) {
        float4 v = reinterpret_cast<const float4*>(loss)[i4];
        unsigned u, p;
        u = fkey(v.x); p = u >> 10;
        if (p > pref22) { asum += fix64(v.x); acnt++; }
        else if (p == pref22) { atomicAdd(&h[u & 1023u], 1u); atomicAdd(&bs[u & 1023u], fix64(v.x)); }
        u = fkey(v.y); p = u >> 10;
        if (p > pref22) { asum += fix64(v.y); acnt++; }
        else if (p == pref22) { atomicAdd(&h[u & 1023u], 1u); atomicAdd(&bs[u & 1023u], fix64(v.y)); }
        u = fkey(v.z); p = u >> 10;
        if (p > pref22) { asum += fix64(v.z); acnt++; }
        else if (p == pref22) { atomicAdd(&h[u & 1023u], 1u); atomicAdd(&bs[u & 1023u], fix64(v.z)); }
        u = fkey(v.w); p = u >> 10;
        if (p > pref22) { asum += fix64(v.w); acnt++; }
        else if (p == pref22) { atomicAdd(&h[u & 1023u], 1u); atomicAdd(&bs[u & 1023u], fix64(v.w)); }
    }
    // block-reduce above partials (integer -> deterministic)
#pragma unroll
    for (int off = 32; off >= 1; off >>= 1) {
        asum += __shfl_down(asum, off);
        acnt += __shfl_down(acnt, off);
    }
    __shared__ unsigned long long wsum[4];
    __shared__ unsigned wcnt[4];
    int wid = threadIdx.x >> 6, lane = threadIdx.x & 63;
    if (lane == 0) { wsum[wid] = asum; wcnt[wid] = acnt; }
    __syncthreads();
    if (threadIdx.x == 0) {
        unsigned long long ts = wsum[0] + wsum[1] + wsum[2] + wsum[3];
        unsigned tc = wcnt[0] + wcnt[1] + wcnt[2] + wcnt[3];
        if (ts) atomicAdd(aboveSum, ts);
        if (tc) atomicAdd(aboveCnt, tc);
    }
    __syncthreads();
    for (int i = threadIdx.x; i < 1024; i += 256) {
        unsigned c = h[i];
        if (c) { atomicAdd(&h3g[i], c); atomicAdd(&bsg[i], bs[i]); }
    }
}

// ---- suffix-scan to find bin holding the k-th largest (passes 0 and 1) ----
template <int PASS>
__global__ __launch_bounds__(256) void k_scan(const unsigned* __restrict__ hist,
                                              SelState* st) {
    __shared__ unsigned chunk[256];
    int t = threadIdx.x;
    unsigned k = (PASS == 0) ? st->num : st->k1;

    unsigned local[8];
    unsigned lsum = 0;
#pragma unroll
    for (int j = 0; j < 8; ++j) { local[j] = hist[t * 8 + j]; lsum += local[j]; }
    chunk[t] = lsum;
    __syncthreads();
    for (int off = 1; off < 256; off <<= 1) {
        unsigned add = (t + off < 256) ? chunk[t + off] : 0u;
        __syncthreads();
        chunk[t] += add;
        __syncthreads();
    }
    unsigned cum = (t < 255) ? chunk[t + 1] : 0u;  // count strictly above my chunk
#pragma unroll
    for (int j = 7; j >= 0; --j) {
        unsigned c = local[j];
        if (k > cum && k <= cum + c) {
            unsigned bin = (unsigned)(t * 8 + j);
            unsigned krem = k - cum;
            if (PASS == 0) { st->b1 = bin; st->k1 = krem; }
            else { st->b2 = bin; st->k2 = krem; }
        }
        cum += c;
    }
}

// ---- last: find b3 in h3, sum bins >= b3 + above partials, write mean ----
__global__ __launch_bounds__(256) void k_last(const unsigned* __restrict__ h3,
                                              const unsigned long long* __restrict__ bsg,
                                              const unsigned long long* __restrict__ aboveSum,
                                              const unsigned* __restrict__ aboveCnt,
                                              const SelState* __restrict__ st,
                                              float* __restrict__ out) {
    __shared__ unsigned chunk[256];
    __shared__ unsigned b3sh;
    __shared__ unsigned long long wsum[4];
    __shared__ unsigned wcnt[4];
    int t = threadIdx.x;
    unsigned k = st->k2;

    unsigned local[4];
    unsigned lsum = 0;
#pragma unroll
    for (int j = 0; j < 4; ++j) { local[j] = h3[t * 4 + j]; lsum += local[j]; }
    chunk[t] = lsum;
    __syncthreads();
    for (int off = 1; off < 256; off <<= 1) {
        unsigned add = (t + off < 256) ? chunk[t + off] : 0u;
        __syncthreads();
        chunk[t] += add;
        __syncthreads();
    }
    unsigned cum = (t < 255) ? chunk[t + 1] : 0u;
#pragma unroll
    for (int j = 3; j >= 0; --j) {
        unsigned c = local[j];
        if (k > cum && k <= cum + c) b3sh = (unsigned)(t * 4 + j);
        cum += c;
    }
    __syncthreads();
    unsigned b3 = b3sh;

    unsigned long long s = 0ull;
    unsigned cnt = 0;
#pragma unroll
    for (int j = 0; j < 4; ++j) {
        unsigned bin = (unsigned)(t * 4 + j);
        if (bin >= b3) { s += bsg[bin]; cnt += local[j]; }
    }
#pragma unroll
    for (int off = 32; off >= 1; off >>= 1) {
        s += __shfl_down(s, off);
        cnt += __shfl_down(cnt, off);
    }
    int wid = t >> 6, lane = t & 63;
    if (lane == 0) { wsum[wid] = s; wcnt[wid] = cnt; }
    __syncthreads();
    if (t == 0) {
        unsigned long long ts = wsum[0] + wsum[1] + wsum[2] + wsum[3] + aboveSum[0];
        unsigned long long tc = (unsigned long long)(wcnt[0] + wcnt[1] + wcnt[2] + wcnt[3])
                              + (unsigned long long)aboveCnt[0];
        out[0] = (float)(((double)ts / FIX_SCALE) / (double)tc);
    }
}

extern "C" void kernel_launch(void* const* d_in, const int* in_sizes, int n_in,
                              void* d_out, int out_size, void* d_ws, size_t ws_size,
                              hipStream_t stream) {
    const float* pred = (const float*)d_in[0];
    const int* target = (const int*)d_in[1];
    const int* step = (const int*)d_in[2];
    float* out = (float*)d_out;

    char* ws = (char*)d_ws;
    const size_t LOSS_BYTES = (size_t)NPIX * 4;  // 16 MiB
    float* loss = (float*)ws;
    char* sb = ws + LOSS_BYTES;
    unsigned* hist1 = (unsigned*)(sb);                       // 2048 u32  @ +0
    unsigned* hist2 = (unsigned*)(sb + 8192);                // 2048 u32  @ +8192
    unsigned* h3 = (unsigned*)(sb + 16384);                  // 1024 u32  @ +16384
    unsigned long long* bs = (unsigned long long*)(sb + 20480); // 1024 u64 @ +20480
    unsigned long long* aboveSum = (unsigned long long*)(sb + 28672); // @ +28672
    unsigned* aboveCnt = (unsigned*)(sb + 28680);            // @ +28680
    SelState* st = (SelState*)(sb + 28688);

    k_init<<<1, 256, 0, stream>>>(step, hist1, st);
    k_loss_hist<<<1024, 256, 0, stream>>>(pred, target, loss, hist1);
    k_scan<0><<<1, 256, 0, stream>>>(hist1, st);
    k_histB<<<1024, 256, 0, stream>>>(loss, st, hist2);
    k_scan<1><<<1, 256, 0, stream>>>(hist2, st);
    k_histC<<<1024, 256, 0, stream>>>(loss, st, h3, bs, aboveSum, aboveCnt);
    k_last<<<1, 256, 0, stream>>>(h3, bs, aboveSum, aboveCnt, st, out);
}

// Round 3
// 115.698 us; speedup vs baseline: 1.2219x; 1.2219x over previous
//
#include <hip/hip_runtime.h>

#define BB 8
#define CCH 19
#define HH 512
#define WW 1024
#define HW (HH * WW)          // 524288
#define NPIX (BB * HW)        // 4194304
#define CHW (CCH * HW)
#define N4 (NPIX / 4)         // 1048576

#define FIX_SCALE 17179869184.0   // 2^34

struct SelState {
    unsigned num;
    unsigned b1, k1;
};

__device__ __forceinline__ unsigned fkey(float x) {
    unsigned u = __float_as_uint(x);
    return (u & 0x80000000u) ? ~u : (u | 0x80000000u);
}

// two's-complement fixed point: safe for tiny negative fp-error losses,
// modular addition stays exact, final total fits i64 (4.2M * 20 * 2^34 < 2^63)
__device__ __forceinline__ unsigned long long fix64(float x) {
    return (unsigned long long)(long long)((double)x * FIX_SCALE);
}

// ---- init: zero all small global state + compute num from step ----
// layout (u32 words from zbase): h1[2048] | h2[2048] | bs2[4096 (u64x2048)] |
//   aboveSum(2) | aboveCnt(1) | pad(1) | st(3)
__global__ __launch_bounds__(256) void k_init(const int* __restrict__ step_p,
                                              unsigned* __restrict__ zbase,
                                              SelState* st) {
    for (int i = threadIdx.x; i < 8448; i += 256) zbase[i] = 0u;
    __syncthreads();
    if (threadIdx.x == 0) {
        int step = step_p[0];
        double m = pow(0.99998, (double)step);
        double Kc = 0.15;
        double f = m > Kc ? m : Kc;
        st->num = (unsigned)(Kc * (double)BB * (double)HH * (double)WW * f);
    }
}

// ---- pass 1: per-pixel CE (float4) + fused 11-bit count histogram ----
__global__ __launch_bounds__(256) void k_loss_hist(const float* __restrict__ pred,
                                                   const int* __restrict__ target,
                                                   float* __restrict__ loss,
                                                   unsigned* __restrict__ hist) {
    __shared__ unsigned h[2048];
    for (int i = threadIdx.x; i < 2048; i += 256) h[i] = 0;
    __syncthreads();

    int stride = gridDim.x * 256;
    for (int i4 = blockIdx.x * 256 + threadIdx.x; i4 < N4; i4 += stride) {
        int p0 = i4 << 2;
        int b = p0 >> 19;           // / HW
        int hw = p0 & (HW - 1);
        const float* base = pred + (size_t)b * CHW + hw;

        float4 v[CCH];
#pragma unroll
        for (int c = 0; c < CCH; ++c)
            v[c] = *reinterpret_cast<const float4*>(base + (size_t)c * HW);
        int4 tg = *reinterpret_cast<const int4*>(target + p0);

        float4 mx = v[0];
#pragma unroll
        for (int c = 1; c < CCH; ++c) {
            mx.x = fmaxf(mx.x, v[c].x);
            mx.y = fmaxf(mx.y, v[c].y);
            mx.z = fmaxf(mx.z, v[c].z);
            mx.w = fmaxf(mx.w, v[c].w);
        }
        float4 s = make_float4(0.f, 0.f, 0.f, 0.f);
        float4 xt = make_float4(0.f, 0.f, 0.f, 0.f);
#pragma unroll
        for (int c = 0; c < CCH; ++c) {
            s.x += __expf(v[c].x - mx.x);
            s.y += __expf(v[c].y - mx.y);
            s.z += __expf(v[c].z - mx.z);
            s.w += __expf(v[c].w - mx.w);
            xt.x = (tg.x == c) ? v[c].x : xt.x;
            xt.y = (tg.y == c) ? v[c].y : xt.y;
            xt.z = (tg.z == c) ? v[c].z : xt.z;
            xt.w = (tg.w == c) ? v[c].w : xt.w;
        }
        float4 o;
        o.x = __logf(s.x) + mx.x - xt.x;
        o.y = __logf(s.y) + mx.y - xt.y;
        o.z = __logf(s.z) + mx.z - xt.z;
        o.w = __logf(s.w) + mx.w - xt.w;
        *reinterpret_cast<float4*>(loss + p0) = o;

        atomicAdd(&h[fkey(o.x) >> 21], 1u);
        atomicAdd(&h[fkey(o.y) >> 21], 1u);
        atomicAdd(&h[fkey(o.z) >> 21], 1u);
        atomicAdd(&h[fkey(o.w) >> 21], 1u);
    }
    __syncthreads();
    for (int i = threadIdx.x; i < 2048; i += 256) {
        unsigned c = h[i];
        if (c) atomicAdd(&hist[i], c);
    }
}

// ---- suffix-scan over h1: find bin b1 holding the num-th largest ----
__global__ __launch_bounds__(256) void k_scan1(const unsigned* __restrict__ hist,
                                               SelState* st) {
    __shared__ unsigned chunk[256];
    int t = threadIdx.x;
    unsigned k = st->num;

    unsigned local[8];
    unsigned lsum = 0;
#pragma unroll
    for (int j = 0; j < 8; ++j) { local[j] = hist[t * 8 + j]; lsum += local[j]; }
    chunk[t] = lsum;
    __syncthreads();
    for (int off = 1; off < 256; off <<= 1) {
        unsigned add = (t + off < 256) ? chunk[t + off] : 0u;
        __syncthreads();
        chunk[t] += add;
        __syncthreads();
    }
    unsigned cum = (t < 255) ? chunk[t + 1] : 0u;  // count strictly above my chunk
#pragma unroll
    for (int j = 7; j >= 0; --j) {
        unsigned c = local[j];
        if (k > cum && k <= cum + c) {
            st->b1 = (unsigned)(t * 8 + j);
            st->k1 = k - cum;
        }
        cum += c;
    }
}

// ---- pass 2: above-b1 elements -> register-accumulated sum/count;
//      in-b1 elements -> 11-bit LDS count+sum histogram ----
__global__ __launch_bounds__(256) void k_hist2(const float* __restrict__ loss,
                                               const SelState* __restrict__ st,
                                               unsigned* __restrict__ h2g,
                                               unsigned long long* __restrict__ bs2g,
                                               unsigned long long* __restrict__ aboveSum,
                                               unsigned* __restrict__ aboveCnt) {
    __shared__ unsigned h[2048];
    __shared__ unsigned long long bs[2048];
    for (int i = threadIdx.x; i < 2048; i += 256) { h[i] = 0; bs[i] = 0ull; }
    __syncthreads();
    unsigned b1 = st->b1;
    unsigned long long asum = 0ull;
    unsigned acnt = 0;
    int stride = gridDim.x * 256;
    for (int i4 = blockIdx.x * 256 + threadIdx.x; i4 < N4; i4 += stride) {
        float4 v = reinterpret_cast<const float4*>(loss)[i4];
        unsigned u, hi;
        u = fkey(v.x); hi = u >> 21;
        if (hi > b1) { asum += fix64(v.x); acnt++; }
        else if (hi == b1) { unsigned idx = (u >> 10) & 2047u; atomicAdd(&h[idx], 1u); atomicAdd(&bs[idx], fix64(v.x)); }
        u = fkey(v.y); hi = u >> 21;
        if (hi > b1) { asum += fix64(v.y); acnt++; }
        else if (hi == b1) { unsigned idx = (u >> 10) & 2047u; atomicAdd(&h[idx], 1u); atomicAdd(&bs[idx], fix64(v.y)); }
        u = fkey(v.z); hi = u >> 21;
        if (hi > b1) { asum += fix64(v.z); acnt++; }
        else if (hi == b1) { unsigned idx = (u >> 10) & 2047u; atomicAdd(&h[idx], 1u); atomicAdd(&bs[idx], fix64(v.z)); }
        u = fkey(v.w); hi = u >> 21;
        if (hi > b1) { asum += fix64(v.w); acnt++; }
        else if (hi == b1) { unsigned idx = (u >> 10) & 2047u; atomicAdd(&h[idx], 1u); atomicAdd(&bs[idx], fix64(v.w)); }
    }
    // deterministic integer block reduction of the "above" partials
#pragma unroll
    for (int off = 32; off >= 1; off >>= 1) {
        asum += __shfl_down(asum, off);
        acnt += __shfl_down(acnt, off);
    }
    __shared__ unsigned long long wsum[4];
    __shared__ unsigned wcnt[4];
    int wid = threadIdx.x >> 6, lane = threadIdx.x & 63;
    if (lane == 0) { wsum[wid] = asum; wcnt[wid] = acnt; }
    __syncthreads();
    if (threadIdx.x == 0) {
        unsigned long long ts = wsum[0] + wsum[1] + wsum[2] + wsum[3];
        unsigned tc = wcnt[0] + wcnt[1] + wcnt[2] + wcnt[3];
        if (ts) atomicAdd(aboveSum, ts);
        if (tc) atomicAdd(aboveCnt, tc);
    }
    __syncthreads();
    for (int i = threadIdx.x; i < 2048; i += 256) {
        unsigned c = h[i];
        if (c) { atomicAdd(&h2g[i], c); atomicAdd(&bs2g[i], bs[i]); }
    }
}

// ---- last: find b2 in h2, include all bins >= b2, add above partials ----
__global__ __launch_bounds__(256) void k_last(const unsigned* __restrict__ h2,
                                              const unsigned long long* __restrict__ bs2,
                                              const unsigned long long* __restrict__ aboveSum,
                                              const unsigned* __restrict__ aboveCnt,
                                              const SelState* __restrict__ st,
                                              float* __restrict__ out) {
    __shared__ unsigned chunk[256];
    __shared__ unsigned b2sh;
    __shared__ unsigned long long wsum[4];
    __shared__ unsigned wcnt[4];
    int t = threadIdx.x;
    unsigned k = st->k1;
    if (t == 0) b2sh = 0u;  // fallback: include whole b1 bin

    unsigned local[8];
    unsigned lsum = 0;
#pragma unroll
    for (int j = 0; j < 8; ++j) { local[j] = h2[t * 8 + j]; lsum += local[j]; }
    chunk[t] = lsum;
    __syncthreads();
    for (int off = 1; off < 256; off <<= 1) {
        unsigned add = (t + off < 256) ? chunk[t + off] : 0u;
        __syncthreads();
        chunk[t] += add;
        __syncthreads();
    }
    unsigned cum = (t < 255) ? chunk[t + 1] : 0u;
#pragma unroll
    for (int j = 7; j >= 0; --j) {
        unsigned c = local[j];
        if (k > cum && k <= cum + c) b2sh = (unsigned)(t * 8 + j);
        cum += c;
    }
    __syncthreads();
    unsigned b2 = b2sh;

    unsigned long long s = 0ull;
    unsigned cnt = 0;
#pragma unroll
    for (int j = 0; j < 8; ++j) {
        unsigned bin = (unsigned)(t * 8 + j);
        if (bin >= b2) { s += bs2[bin]; cnt += local[j]; }
    }
#pragma unroll
    for (int off = 32; off >= 1; off >>= 1) {
        s += __shfl_down(s, off);
        cnt += __shfl_down(cnt, off);
    }
    int wid = t >> 6, lane = t & 63;
    if (lane == 0) { wsum[wid] = s; wcnt[wid] = cnt; }
    __syncthreads();
    if (t == 0) {
        unsigned long long ts = wsum[0] + wsum[1] + wsum[2] + wsum[3] + aboveSum[0];
        unsigned long long tc = (unsigned long long)(wcnt[0] + wcnt[1] + wcnt[2] + wcnt[3])
                              + (unsigned long long)aboveCnt[0];
        long long ss = (long long)ts;
        out[0] = (float)(((double)ss / FIX_SCALE) / (double)tc);
    }
}

extern "C" void kernel_launch(void* const* d_in, const int* in_sizes, int n_in,
                              void* d_out, int out_size, void* d_ws, size_t ws_size,
                              hipStream_t stream) {
    const float* pred = (const float*)d_in[0];
    const int* target = (const int*)d_in[1];
    const int* step = (const int*)d_in[2];
    float* out = (float*)d_out;

    char* ws = (char*)d_ws;
    const size_t LOSS_BYTES = (size_t)NPIX * 4;  // 16 MiB
    float* loss = (float*)ws;
    char* sb = ws + LOSS_BYTES;
    unsigned* h1 = (unsigned*)(sb);                            // 2048 u32 @ +0
    unsigned* h2 = (unsigned*)(sb + 8192);                     // 2048 u32 @ +8192
    unsigned long long* bs2 = (unsigned long long*)(sb + 16384);  // 2048 u64 @ +16384
    unsigned long long* aboveSum = (unsigned long long*)(sb + 32768);
    unsigned* aboveCnt = (unsigned*)(sb + 32776);
    SelState* st = (SelState*)(sb + 32784);

    k_init<<<1, 256, 0, stream>>>(step, h1, st);
    k_loss_hist<<<1024, 256, 0, stream>>>(pred, target, loss, h1);
    k_scan1<<<1, 256, 0, stream>>>(h1, st);
    k_hist2<<<1024, 256, 0, stream>>>(loss, st, h2, bs2, aboveSum, aboveCnt);
    k_last<<<1, 256, 0, stream>>>(h2, bs2, aboveSum, aboveCnt, st, out);
}